// Round 6
// baseline (146.423 us; speedup 1.0000x reference)
//
#include <hip/hip_runtime.h>
#include <hip/hip_bf16.h>

// 3x3 VALID conv via bf16 MFMA implicit GEMM.
// x: (64,224,224) fp32, w: (128,64,3,3) fp32, out: (128,222,222) fp32.
//
// R6: MEASUREMENT ROUND. Identical to R5 except conv_mfma_kernel is
// dispatched TWICE (idempotent: rewrites the same values). The dur_us
// delta vs R5 isolates conv's true duration, which rocprof's top-5
// (all ~44us harness poison-fills) has been hiding.

#define H_IN   224
#define W_IN   224
#define C_OUT  128
#define H_OUT  222
#define W_OUT  222
#define XP     226   // padded spatial extent of xt
#define CPAD   72    // padded c stride in conv LDS
#define TW     68    // padded w stride in transpose LDS

typedef __attribute__((ext_vector_type(8))) short bf16x8;
typedef __attribute__((ext_vector_type(4))) float f32x4;

static __device__ __forceinline__ unsigned short f2bs(float f) {
    union { __hip_bfloat16 h; unsigned short u; } cv;
    cv.h = __float2bfloat16(f);
    return cv.u;
}

__global__ __launch_bounds__(256)
void transform_w_kernel(const float* __restrict__ w, __hip_bfloat16* __restrict__ wt)
{
    int idx = blockIdx.x * 256 + threadIdx.x;     // [ij][co][c], 9*128*64
    if (idx < 9 * 128 * 64) {
        int ij  = idx >> 13;
        int rem = idx & 8191;
        int co  = rem >> 6;
        int c   = rem & 63;
        wt[idx] = __float2bfloat16(w[(co * 64 + c) * 9 + ij]);
    }
}

__global__ __launch_bounds__(256)
void transpose_x_kernel(const float* __restrict__ x, __hip_bfloat16* __restrict__ xt)
{
    __shared__ __align__(16) unsigned short tile[64 * TW];   // [c][w_local]
    const int h  = blockIdx.y;                 // 0..225
    const int w0 = blockIdx.x * 64;            // 0,64,128,192
    const int t  = threadIdx.x;

    // Phase 1: coalesced float4 reads along w; zeros for padded h/w.
    {
        const int wq = (t & 15) * 4;           // 0..60 (lanes contiguous in w)
        const int c0 = t >> 4;                 // 0..15
        #pragma unroll
        for (int p = 0; p < 4; ++p) {
            const int c  = c0 + p * 16;
            const int wg = w0 + wq;
            float4 v = make_float4(0.f, 0.f, 0.f, 0.f);
            if (h < H_IN && wg < W_IN)         // wg%4==0, W_IN%4==0 -> all-or-nothing
                v = *(const float4*)(x + ((size_t)c * H_IN + h) * W_IN + wg);
            ushort4 b;
            b.x = f2bs(v.x); b.y = f2bs(v.y); b.z = f2bs(v.z); b.w = f2bs(v.w);
            *(ushort4*)(tile + c * TW + wq) = b;   // (c*136 + wq*2) % 8 == 0
        }
    }
    __syncthreads();

    // Phase 2: gather 16 c per thread from LDS, contiguous 16B/lane stores.
    {
        const int wl = t >> 2;                 // 0..63
        const int cq = (t & 3) * 16;           // 0,16,32,48
        const int wg = w0 + wl;
        if (wg < XP) {
            alignas(16) unsigned short r[16];
            #pragma unroll
            for (int k = 0; k < 16; ++k)
                r[k] = tile[(cq + k) * TW + wl];
            float4* d = (float4*)((unsigned short*)xt + ((size_t)h * XP + wg) * 64 + cq);
            d[0] = ((const float4*)r)[0];
            d[1] = ((const float4*)r)[1];
        }
    }
}

__global__ __launch_bounds__(256)
void conv_mfma_kernel(const __hip_bfloat16* __restrict__ xt,
                      const __hip_bfloat16* __restrict__ wt,
                      float* __restrict__ out)
{
    __shared__ __hip_bfloat16 xs[10 * 18 * CPAD];  // [row][wc][c] = 25,920 B
    const int ow0 = blockIdx.x * 16;
    const int oh0 = blockIdx.y * 8;
    const int co0 = blockIdx.z * 64;
    const int tid = threadIdx.x;

    // Stage x tile: rows oh0..oh0+9, cols ow0..ow0+17, all 64 c (bf16).
    for (int q = tid; q < 10 * 18 * 8; q += 256) {
        int sub = q & 7;
        int pix = q >> 3;
        int row = pix / 18;
        int wc  = pix - row * 18;
        const float4* s = (const float4*)(xt + ((oh0 + row) * XP + (ow0 + wc)) * 64 + sub * 8);
        float4*       d = (float4*)(xs + (row * 18 + wc) * CPAD + sub * 8);
        *d = *s;
    }
    __syncthreads();

    const int wave = tid >> 6;
    const int lane = tid & 63;
    const int lq   = lane >> 4;    // quad 0..3
    const int lm   = lane & 15;
    const int r0   = wave * 2;     // this wave's 2 output rows

    f32x4 acc[2][4] = {};

    #pragma unroll 3
    for (int ij = 0; ij < 9; ++ij) {
        const int i = ij / 3;
        const int j = ij - i * 3;
        bf16x8 afr[2][4];
        #pragma unroll
        for (int t = 0; t < 2; ++t)
            #pragma unroll
            for (int ms = 0; ms < 4; ++ms)
                afr[t][ms] = *(const bf16x8*)(wt +
                    ((ij * 128 + co0 + ms * 16 + lm) * 64 + t * 32 + lq * 8));
        #pragma unroll
        for (int rr = 0; rr < 2; ++rr) {
            const int r = r0 + rr;
            #pragma unroll
            for (int t = 0; t < 2; ++t) {
                bf16x8 bfr = *(const bf16x8*)(xs +
                    ((i + r) * 18 + lm + j) * CPAD + t * 32 + lq * 8);
                #pragma unroll
                for (int ms = 0; ms < 4; ++ms)
                    acc[rr][ms] = __builtin_amdgcn_mfma_f32_16x16x32_bf16(
                        afr[t][ms], bfr, acc[rr][ms], 0, 0, 0);
            }
        }
    }

    // Epilogue: D col(ow)=lm, row(co offset)=lq*4+d
    #pragma unroll
    for (int rr = 0; rr < 2; ++rr) {
        int oh = oh0 + r0 + rr;
        int ow = ow0 + lm;
        if (oh < H_OUT && ow < W_OUT) {
            #pragma unroll
            for (int ms = 0; ms < 4; ++ms) {
                int co = co0 + ms * 16 + lq * 4;
                #pragma unroll
                for (int d = 0; d < 4; ++d)
                    out[(co + d) * (H_OUT * W_OUT) + oh * W_OUT + ow] = acc[rr][ms][d];
            }
        }
    }
}

extern "C" void kernel_launch(void* const* d_in, const int* in_sizes, int n_in,
                              void* d_out, int out_size, void* d_ws, size_t ws_size,
                              hipStream_t stream)
{
    const float* x = (const float*)d_in[0];
    const float* w = (const float*)d_in[1];
    float* out     = (float*)d_out;

    __hip_bfloat16* xt = (__hip_bfloat16*)d_ws;                      // 226*226*64*2 B
    __hip_bfloat16* wt = (__hip_bfloat16*)((char*)d_ws + (size_t)XP * XP * 64 * 2);

    transform_w_kernel<<<288, 256, 0, stream>>>(w, wt);
    transpose_x_kernel<<<dim3(4, XP), 256, 0, stream>>>(x, xt);
    conv_mfma_kernel<<<dim3(14, 28, 2), 256, 0, stream>>>(xt, wt, out);
    // Second, idempotent conv dispatch: dur_us(R6) - dur_us(R5) = conv time.
    conv_mfma_kernel<<<dim3(14, 28, 2), 256, 0, stream>>>(xt, wt, out);
}

// Round 7
// 88.783 us; speedup vs baseline: 1.6492x; 1.6492x over previous
//
#include <hip/hip_runtime.h>
#include <hip/hip_bf16.h>

// 3x3 VALID conv via bf16 MFMA implicit GEMM.
// x: (64,224,224) fp32, w: (128,64,3,3) fp32, out: (128,222,222) fp32.
//
// R7: conv restructured to the m97 pattern — ALL MFMA operands from LDS.
// R6 evidence: conv=38us, MfmaUtil 6%, VALUBusy 8%, occupancy 24%, VGPR 56
// -> per-wave serialized global weight-load latency chains. Fix: weights
// cooperatively staged into LDS per filter row (3 taps, co-stride padded
// 64->72 ushorts for bank-floor ds_read_b128), compute loop is pure
// LDS->MFMA. Static LDS = 25,920(xs) + 27,648(ws) = 53,568 B -> 3 blocks/CU.

#define H_IN   224
#define W_IN   224
#define C_OUT  128
#define H_OUT  222
#define W_OUT  222
#define XP     226   // padded spatial extent of xt
#define CPAD   72    // padded c stride in conv x-LDS
#define WPAD   72    // padded c stride in conv w-LDS
#define TW     68    // padded w stride in transpose LDS

typedef __attribute__((ext_vector_type(8))) short bf16x8;
typedef __attribute__((ext_vector_type(4))) float f32x4;

static __device__ __forceinline__ unsigned short f2bs(float f) {
    union { __hip_bfloat16 h; unsigned short u; } cv;
    cv.h = __float2bfloat16(f);
    return cv.u;
}

__global__ __launch_bounds__(256)
void transform_w_kernel(const float* __restrict__ w, __hip_bfloat16* __restrict__ wt)
{
    int idx = blockIdx.x * 256 + threadIdx.x;     // [ij][co][c], 9*128*64
    if (idx < 9 * 128 * 64) {
        int ij  = idx >> 13;
        int rem = idx & 8191;
        int co  = rem >> 6;
        int c   = rem & 63;
        wt[idx] = __float2bfloat16(w[(co * 64 + c) * 9 + ij]);
    }
}

__global__ __launch_bounds__(256)
void transpose_x_kernel(const float* __restrict__ x, __hip_bfloat16* __restrict__ xt)
{
    __shared__ __align__(16) unsigned short tile[64 * TW];   // [c][w_local]
    const int h  = blockIdx.y;                 // 0..225
    const int w0 = blockIdx.x * 64;            // 0,64,128,192
    const int t  = threadIdx.x;

    // Phase 1: coalesced float4 reads along w; zeros for padded h/w.
    {
        const int wq = (t & 15) * 4;           // 0..60 (lanes contiguous in w)
        const int c0 = t >> 4;                 // 0..15
        #pragma unroll
        for (int p = 0; p < 4; ++p) {
            const int c  = c0 + p * 16;
            const int wg = w0 + wq;
            float4 v = make_float4(0.f, 0.f, 0.f, 0.f);
            if (h < H_IN && wg < W_IN)         // wg%4==0, W_IN%4==0 -> all-or-nothing
                v = *(const float4*)(x + ((size_t)c * H_IN + h) * W_IN + wg);
            ushort4 b;
            b.x = f2bs(v.x); b.y = f2bs(v.y); b.z = f2bs(v.z); b.w = f2bs(v.w);
            *(ushort4*)(tile + c * TW + wq) = b;   // (c*136 + wq*2) % 8 == 0
        }
    }
    __syncthreads();

    // Phase 2: gather 16 c per thread from LDS, contiguous 16B/lane stores.
    {
        const int wl = t >> 2;                 // 0..63
        const int cq = (t & 3) * 16;           // 0,16,32,48
        const int wg = w0 + wl;
        if (wg < XP) {
            alignas(16) unsigned short r[16];
            #pragma unroll
            for (int k = 0; k < 16; ++k)
                r[k] = tile[(cq + k) * TW + wl];
            float4* d = (float4*)((unsigned short*)xt + ((size_t)h * XP + wg) * 64 + cq);
            d[0] = ((const float4*)r)[0];
            d[1] = ((const float4*)r)[1];
        }
    }
}

__global__ __launch_bounds__(256)
void conv_mfma_kernel(const __hip_bfloat16* __restrict__ xt,
                      const __hip_bfloat16* __restrict__ wt,
                      float* __restrict__ out)
{
    __shared__ __hip_bfloat16 xs[10 * 18 * CPAD];   // [row][wc][c]   25,920 B
    __shared__ __hip_bfloat16 ws[3 * 64 * WPAD];    // [tap][co][c]   27,648 B
    const int ow0 = blockIdx.x * 16;
    const int oh0 = blockIdx.y * 8;
    const int co0 = blockIdx.z * 64;
    const int tid = threadIdx.x;

    const int wave = tid >> 6;
    const int lane = tid & 63;
    const int lq   = lane >> 4;    // quad 0..3
    const int lm   = lane & 15;
    const int r0   = wave * 2;     // this wave's 2 output rows

    // Stage x tile once: rows oh0..oh0+9, cols ow0..ow0+17, all 64 c.
    for (int q = tid; q < 10 * 18 * 8; q += 256) {
        int sub = q & 7;
        int pix = q >> 3;
        int row = pix / 18;
        int wc  = pix - row * 18;
        *(float4*)(xs + (row * 18 + wc) * CPAD + sub * 8) =
            *(const float4*)(xt + ((oh0 + row) * XP + (ow0 + wc)) * 64 + sub * 8);
    }

    f32x4 acc[2][4] = {};

    #pragma unroll
    for (int i = 0; i < 3; ++i) {          // filter row
        // Stage this row's 3 taps of weights (co0..co0+63) into ws.
        if (i > 0) __syncthreads();        // all waves done reading ws from row i-1
        #pragma unroll
        for (int k = 0; k < 6; ++k) {      // 1536 16B-chunks / 256 threads
            int q   = k * 256 + tid;
            int jj  = q >> 9;              // tap within row (0..2)
            int r   = q & 511;
            int co  = r >> 3;              // 0..63
            int sub = r & 7;               // 16B chunk within 128B c-row
            *(float4*)(ws + (jj * 64 + co) * WPAD + sub * 8) =
                *(const float4*)(wt + ((i * 3 + jj) * 128 + co0 + co) * 64 + sub * 8);
        }
        __syncthreads();                   // row i weights (and xs on i==0) visible

        #pragma unroll
        for (int jj = 0; jj < 3; ++jj) {
            bf16x8 afr[2][4];
            #pragma unroll
            for (int t = 0; t < 2; ++t)
                #pragma unroll
                for (int ms = 0; ms < 4; ++ms)
                    afr[t][ms] = *(const bf16x8*)(ws +
                        (jj * 64 + ms * 16 + lm) * WPAD + t * 32 + lq * 8);
            #pragma unroll
            for (int rr = 0; rr < 2; ++rr) {
                #pragma unroll
                for (int t = 0; t < 2; ++t) {
                    bf16x8 bfr = *(const bf16x8*)(xs +
                        ((i + r0 + rr) * 18 + lm + jj) * CPAD + t * 32 + lq * 8);
                    #pragma unroll
                    for (int ms = 0; ms < 4; ++ms)
                        acc[rr][ms] = __builtin_amdgcn_mfma_f32_16x16x32_bf16(
                            afr[t][ms], bfr, acc[rr][ms], 0, 0, 0);
                }
            }
        }
    }

    // Epilogue: D col(ow)=lm, row(co offset)=lq*4+d
    #pragma unroll
    for (int rr = 0; rr < 2; ++rr) {
        int oh = oh0 + r0 + rr;
        int ow = ow0 + lm;
        if (oh < H_OUT && ow < W_OUT) {
            #pragma unroll
            for (int ms = 0; ms < 4; ++ms) {
                int co = co0 + ms * 16 + lq * 4;
                #pragma unroll
                for (int d = 0; d < 4; ++d)
                    out[(co + d) * (H_OUT * W_OUT) + oh * W_OUT + ow] = acc[rr][ms][d];
            }
        }
    }
}

extern "C" void kernel_launch(void* const* d_in, const int* in_sizes, int n_in,
                              void* d_out, int out_size, void* d_ws, size_t ws_size,
                              hipStream_t stream)
{
    const float* x = (const float*)d_in[0];
    const float* w = (const float*)d_in[1];
    float* out     = (float*)d_out;

    __hip_bfloat16* xt = (__hip_bfloat16*)d_ws;                      // 226*226*64*2 B
    __hip_bfloat16* wt = (__hip_bfloat16*)((char*)d_ws + (size_t)XP * XP * 64 * 2);

    transform_w_kernel<<<288, 256, 0, stream>>>(w, wt);
    transpose_x_kernel<<<dim3(4, XP), 256, 0, stream>>>(x, xt);
    conv_mfma_kernel<<<dim3(14, 28, 2), 256, 0, stream>>>(xt, wt, out);
}